// Round 5
// baseline (240.699 us; speedup 1.0000x reference)
//
#include <hip/hip_runtime.h>
#include <cstdint>
#include <cstddef>

// ---------------------------------------------------------------------------
// Attention_Param_sharing_Kv_sharing: B=4, C=256, H=W=64 (N=4096), KD=16,
// NH=8, DH=128.  qk projection shared between Q and K (Gram matrix), one KV
// head shared across 8 heads -> O = softmax(qk^T qk) @ V, V in R^{N x 128}.
// Flash-style fused attention in FP16 MFMA.
//
// R4: passed at 175 us; attn_kernel 137 us with Occupancy 11% (1 wave/SIMD,
// pure latency-bound).  R5: (1) key-split x4 -> 1024 blocks, partial
// (O~,m,l) fp32 in ws + combine kernel (falls back to split=1 if ws_size
// too small); (2) proj_qkv computes all 9 o-tiles per block (x read 1x
// instead of 9x).  Inner attention loop kept byte-identical to the
// verified R4 version.
// ---------------------------------------------------------------------------

typedef __attribute__((ext_vector_type(4))) float f32x4;
typedef __attribute__((ext_vector_type(8))) _Float16 half8;
typedef __attribute__((ext_vector_type(8))) unsigned short ushort8;

#define N_SP 4096
#define CIN  256
#define KDIM 16
#define DHV  128

__device__ __forceinline__ unsigned short f2h(float f) {
    _Float16 h = (_Float16)f;             // RNE
    return __builtin_bit_cast(unsigned short, h);
}

__device__ __forceinline__ f32x4 mfma16(ushort8 a, ushort8 b, f32x4 c) {
    return __builtin_amdgcn_mfma_f32_16x16x32_f16(
        __builtin_bit_cast(half8, a), __builtin_bit_cast(half8, b), c, 0, 0, 0);
}

// ---------------------------------------------------------------------------
// Kernel 0: fold BN into weights (unchanged).
// ---------------------------------------------------------------------------
__global__ __launch_bounds__(256) void fold_weights(
    const float* __restrict__ w_qk, const float* __restrict__ g_qk,
    const float* __restrict__ b_qk, const float* __restrict__ m_qk,
    const float* __restrict__ v_qk,
    const float* __restrict__ w_v, const float* __restrict__ g_v,
    const float* __restrict__ b_v, const float* __restrict__ m_v,
    const float* __restrict__ v_v,
    const float* __restrict__ w_p, const float* __restrict__ g_p,
    const float* __restrict__ b_p, const float* __restrict__ m_p,
    const float* __restrict__ v_p,
    unsigned short* __restrict__ wf1, float* __restrict__ shift1,
    unsigned short* __restrict__ wpf, float* __restrict__ shiftp)
{
    int row = blockIdx.x;
    int t   = threadIdx.x;
    if (row < 144) {
        float s, sh; const float* src;
        if (row < KDIM) {
            s  = g_qk[row] * rsqrtf(v_qk[row] + 1e-5f);
            sh = b_qk[row] - m_qk[row] * s;
            src = w_qk + row * CIN;
        } else {
            int o = row - KDIM;
            s  = g_v[o] * rsqrtf(v_v[o] + 1e-5f);
            sh = b_v[o] - m_v[o] * s;
            src = w_v + o * CIN;
        }
        wf1[row * CIN + t] = f2h(src[t] * s);
        if (t == 0) shift1[row] = sh;
    } else {
        int o = row - 144;
        float s = g_p[o] * rsqrtf(v_p[o] + 1e-5f);
        if (t < DHV) wpf[o * DHV + t] = f2h(w_p[o * DHV + t] * s);
        if (t == 0) shiftp[o] = b_p[o] - m_p[o] * s;
    }
}

// ---------------------------------------------------------------------------
// Kernel 1: projection GEMM  [144 x 256] @ [256 x 4096] per batch.
// Grid (64, B): one block per 64-n tile; computes ALL 9 o-tiles so the
// x B-fragment is loaded once per ks and reused by 9 MFMAs (x read 1x).
// ---------------------------------------------------------------------------
__global__ __launch_bounds__(256) void proj_qkv(
    const float* __restrict__ x,
    const unsigned short* __restrict__ wf1, const float* __restrict__ shift1,
    unsigned short* __restrict__ qkT, unsigned short* __restrict__ Vt)
{
    const int b  = blockIdx.y;
    const int n0 = blockIdx.x * 64;
    const int tid  = threadIdx.x;
    const int w    = tid >> 6;
    const int lane = tid & 63;
    const int lg   = lane >> 4;
    const int lr   = lane & 15;
    const int n    = n0 + w * 16 + lr;

    const float* xb = x + (size_t)b * CIN * N_SP;
    f32x4 acc[9];
#pragma unroll
    for (int i = 0; i < 9; ++i) acc[i] = (f32x4){0.f, 0.f, 0.f, 0.f};

    for (int ks = 0; ks < 8; ++ks) {
        const int cbase = ks * 32 + lg * 8;
        ushort8 bx;
#pragma unroll
        for (int j = 0; j < 8; ++j) {
            float xv = xb[(size_t)(cbase + j) * N_SP + n];
            bx[j] = f2h(xv);
        }
#pragma unroll
        for (int ot = 0; ot < 9; ++ot) {
            ushort8 a = *(const ushort8*)(wf1 + (ot * 16 + lr) * CIN + cbase);
            acc[ot] = mfma16(a, bx, acc[ot]);
        }
    }

#pragma unroll
    for (int ot = 0; ot < 9; ++ot)
#pragma unroll
        for (int r = 0; r < 4; ++r) {
            int o = ot * 16 + lg * 4 + r;
            float val = acc[ot][r] + shift1[o];
            unsigned short hv = f2h(val);
            if (o < KDIM) qkT[((size_t)b * N_SP + n) * 32 + o] = hv;
            else          Vt[((size_t)b * DHV + (o - KDIM)) * N_SP + n] = hv;
        }

    // zero the K-padding columns 16..31 of qkT for this (b, n-tile)
    {
        int n_l  = tid >> 2;
        int part = tid & 3;
        unsigned long long* p = (unsigned long long*)
            (qkT + ((size_t)b * N_SP + n0 + n_l) * 32 + 16 + part * 4);
        *p = 0ULL;
    }
}

// ---------------------------------------------------------------------------
// Kernel 2: flash attention.  Grid (64, B, NSPLIT), 256 thr = 4 waves.
// Wave w owns 16 query rows; loops 64-key tiles over its key split.
// Inner loop identical to the verified R4 kernel.  Epilogue: NSPLIT==1 ->
// normalize+relu -> xx;  NSPLIT>1 -> unnormalized fp32 partials + (m,l).
// ---------------------------------------------------------------------------
__global__ __launch_bounds__(256) void attn_kernel(
    const unsigned short* __restrict__ qkT,
    const unsigned short* __restrict__ Vt,
    unsigned short* __restrict__ xx,
    float* __restrict__ Op, float* __restrict__ mp, float* __restrict__ lp,
    int nsplit)
{
    const int b  = blockIdx.y;
    const int sp = blockIdx.z;
    const int q0 = blockIdx.x * 64;
    const int tid  = threadIdx.x;
    const int w    = tid >> 6;
    const int lane = tid & 63;
    const int lg   = lane >> 4;
    const int lr   = lane & 15;

    const unsigned short* qk_b = qkT + (size_t)b * N_SP * 32;
    const unsigned short* vt_b = Vt  + (size_t)b * DHV * N_SP;
    const int qrow = q0 + w * 16;

    const int kspan = N_SP / nsplit;
    const int kbeg  = sp * kspan;
    const int kend  = kbeg + kspan;

    const ushort8 aq = *(const ushort8*)(qk_b + (size_t)(qrow + lr) * 32 + lg * 8);

    f32x4 acc[8];
#pragma unroll
    for (int i = 0; i < 8; ++i) acc[i] = (f32x4){0.f, 0.f, 0.f, 0.f};
    float m_r[4] = {-__builtin_inff(), -__builtin_inff(),
                    -__builtin_inff(), -__builtin_inff()};
    float l_r[4] = {0.f, 0.f, 0.f, 0.f};

    __shared__ __align__(16) unsigned short p_lds[4][16][72];   // 64 keys + 8 pad

    const f32x4 zero4 = {0.f, 0.f, 0.f, 0.f};

    for (int k0 = kbeg; k0 < kend; k0 += 64) {
        // ---- S = Q K^T for this wave's 16 queries x 64 keys -------------
        f32x4 s[4];
#pragma unroll
        for (int t = 0; t < 4; ++t) {
            ushort8 bk = *(const ushort8*)(qk_b + (size_t)(k0 + t * 16 + lr) * 32 + lg * 8);
            s[t] = mfma16(aq, bk, zero4);
        }

        // ---- hoist V-tile loads so L2 latency overlaps the softmax VALU --
        ushort8 vb[2][8];
#pragma unroll
        for (int ks = 0; ks < 2; ++ks)
#pragma unroll
            for (int nn = 0; nn < 8; ++nn)
                vb[ks][nn] = *(const ushort8*)
                    (vt_b + (size_t)(nn * 16 + lr) * N_SP + k0 + ks * 32 + lg * 8);

        // ---- online softmax (rows = lg*4+r, reduce over lane&15) ---------
        float sc_r[4];
#pragma unroll
        for (int r = 0; r < 4; ++r) {
            float mx = fmaxf(fmaxf(s[0][r], s[1][r]), fmaxf(s[2][r], s[3][r]));
            mx = fmaxf(mx, __shfl_xor(mx, 1));
            mx = fmaxf(mx, __shfl_xor(mx, 2));
            mx = fmaxf(mx, __shfl_xor(mx, 4));
            mx = fmaxf(mx, __shfl_xor(mx, 8));
            float mnew = fmaxf(m_r[r], mx);
            float sc = __expf(m_r[r] - mnew);     // first iter: exp(-inf)=0
            float rs = 0.f;
#pragma unroll
            for (int t = 0; t < 4; ++t) {
                float p = __expf(s[t][r] - mnew);
                s[t][r] = p;
                rs += p;
            }
            rs += __shfl_xor(rs, 1);
            rs += __shfl_xor(rs, 2);
            rs += __shfl_xor(rs, 4);
            rs += __shfl_xor(rs, 8);
            l_r[r] = l_r[r] * sc + rs;
            m_r[r] = mnew;
            sc_r[r] = sc;
        }

        // ---- rescale accumulator ----------------------------------------
#pragma unroll
        for (int nn = 0; nn < 8; ++nn)
#pragma unroll
            for (int r = 0; r < 4; ++r) acc[nn][r] *= sc_r[r];

        // ---- P -> LDS transpose (per-wave region, no barrier needed) -----
#pragma unroll
        for (int t = 0; t < 4; ++t)
#pragma unroll
            for (int r = 0; r < 4; ++r)
                p_lds[w][lg * 4 + r][t * 16 + lr] = f2h(s[t][r]);

        // ---- O += P @ V --------------------------------------------------
#pragma unroll
        for (int ks = 0; ks < 2; ++ks) {
            ushort8 pa = *(const ushort8*)(&p_lds[w][lr][ks * 32 + lg * 8]);
#pragma unroll
            for (int nn = 0; nn < 8; ++nn)
                acc[nn] = mfma16(pa, vb[ks][nn], acc[nn]);
        }
    }

    if (nsplit == 1) {
        // ---- epilogue: divide, relu, store xx[b][q][128] f16 -------------
        const size_t xoff = (size_t)b * N_SP * DHV;
#pragma unroll
        for (int r = 0; r < 4; ++r) {
            float inv = 1.0f / l_r[r];
            int q = qrow + lg * 4 + r;
#pragma unroll
            for (int nn = 0; nn < 8; ++nn) {
                float v = acc[nn][r] * inv;
                v = fmaxf(v, 0.f);
                xx[xoff + (size_t)q * DHV + nn * 16 + lr] = f2h(v);
            }
        }
    } else {
        // ---- partial epilogue: unnormalized O + (m,l) per q-row ----------
#pragma unroll
        for (int r = 0; r < 4; ++r) {
            int q = qrow + lg * 4 + r;
            size_t ro = (size_t)sp * (4 * N_SP) + (size_t)b * N_SP + q;
#pragma unroll
            for (int nn = 0; nn < 8; ++nn)
                Op[ro * DHV + nn * 16 + lr] = acc[nn][r];
            if (lr == 0) { mp[ro] = m_r[r]; lp[ro] = l_r[r]; }
        }
    }
}

// ---------------------------------------------------------------------------
// Kernel 2b: combine key-split partials.  Grid (B*N/2), 256 thr = 2 rows.
// ---------------------------------------------------------------------------
__global__ __launch_bounds__(256) void combine_splits(
    const float* __restrict__ Op, const float* __restrict__ mp,
    const float* __restrict__ lp, unsigned short* __restrict__ xx, int nsplit)
{
    const int row = blockIdx.x * 2 + (threadIdx.x >> 7);    // b*N + q
    const int d   = threadIdx.x & 127;
    const int stride = 4 * N_SP;

    float M = -__builtin_inff();
    for (int s = 0; s < nsplit; ++s) M = fmaxf(M, mp[s * stride + row]);
    float o = 0.f, L = 0.f;
    for (int s = 0; s < nsplit; ++s) {
        float wgt = __expf(mp[s * stride + row] - M);
        o += wgt * Op[((size_t)s * stride + row) * DHV + d];
        L += wgt * lp[s * stride + row];
    }
    xx[(size_t)row * DHV + d] = f2h(fmaxf(o / L, 0.f));
}

// ---------------------------------------------------------------------------
// Kernel 3: output projection (unchanged).
// ---------------------------------------------------------------------------
__global__ __launch_bounds__(256) void proj_out(
    const unsigned short* __restrict__ xx,
    const unsigned short* __restrict__ wpf, const float* __restrict__ shiftp,
    float* __restrict__ out)
{
    const int b  = blockIdx.z;
    const int n0 = blockIdx.y * 64;
    const int o0 = blockIdx.x * 64 + (threadIdx.x >> 6) * 16;
    const int lane = threadIdx.x & 63;
    const int lg   = lane >> 4;
    const int lr   = lane & 15;

    f32x4 acc[4];
#pragma unroll
    for (int i = 0; i < 4; ++i) acc[i] = (f32x4){0.f, 0.f, 0.f, 0.f};

    const unsigned short* xb = xx + (size_t)b * N_SP * DHV;

    for (int ks = 0; ks < 4; ++ks) {
        ushort8 a = *(const ushort8*)(wpf + (size_t)(o0 + lr) * DHV + ks * 32 + lg * 8);
#pragma unroll
        for (int nt = 0; nt < 4; ++nt) {
            ushort8 bfr = *(const ushort8*)
                (xb + (size_t)(n0 + nt * 16 + lr) * DHV + ks * 32 + lg * 8);
            acc[nt] = mfma16(a, bfr, acc[nt]);
        }
    }

#pragma unroll
    for (int nt = 0; nt < 4; ++nt)
#pragma unroll
        for (int r = 0; r < 4; ++r) {
            int o = o0 + lg * 4 + r;
            out[((size_t)b * CIN + o) * N_SP + n0 + nt * 16 + lr]
                = acc[nt][r] + shiftp[o];
        }
}

// ---------------------------------------------------------------------------
extern "C" void kernel_launch(void* const* d_in, const int* in_sizes, int n_in,
                              void* d_out, int out_size, void* d_ws, size_t ws_size,
                              hipStream_t stream)
{
    const float* x    = (const float*)d_in[0];
    const float* w_qk = (const float*)d_in[2];
    const float* g_qk = (const float*)d_in[3];
    const float* b_qk = (const float*)d_in[4];
    const float* m_qk = (const float*)d_in[5];
    const float* v_qk = (const float*)d_in[6];
    const float* w_v  = (const float*)d_in[7];
    const float* g_v  = (const float*)d_in[8];
    const float* b_v  = (const float*)d_in[9];
    const float* m_v  = (const float*)d_in[10];
    const float* v_v  = (const float*)d_in[11];
    const float* w_p  = (const float*)d_in[12];
    const float* g_p  = (const float*)d_in[13];
    const float* b_p  = (const float*)d_in[14];
    const float* m_p  = (const float*)d_in[15];
    const float* v_p  = (const float*)d_in[16];

    char* ws = (char*)d_ws;
    unsigned short* qkT = (unsigned short*)(ws);                    // 1 MB
    unsigned short* Vt  = (unsigned short*)(ws + (1u << 20));       // 4 MB
    unsigned short* xxb = (unsigned short*)(ws + (5u << 20));       // 4 MB
    unsigned short* wf1 = (unsigned short*)(ws + (9u << 20));       // 72 KB
    float* shift1       = (float*)(ws + (9u << 20) + 80 * 1024);    // 576 B
    unsigned short* wpf = (unsigned short*)(ws + (9u << 20) + 84 * 1024); // 64 KB
    float* shiftp       = (float*)(ws + (9u << 20) + 148 * 1024);   // 1 KB
    // key-split partials (only used when nsplit > 1):
    float* Op = (float*)(ws + (16ull << 20));                       // 32 MB @ 16M
    float* mp = (float*)(ws + (48ull << 20));                       // 256 KB
    float* lp = (float*)(ws + (48ull << 20) + (512ull << 10));      // 256 KB

    const size_t need = (49ull << 20);
    const int nsplit = (ws_size >= need) ? 4 : 1;

    fold_weights<<<400, 256, 0, stream>>>(
        w_qk, g_qk, b_qk, m_qk, v_qk,
        w_v, g_v, b_v, m_v, v_v,
        w_p, g_p, b_p, m_p, v_p,
        wf1, shift1, wpf, shiftp);

    proj_qkv<<<dim3(64, 4), 256, 0, stream>>>(x, wf1, shift1, qkT, Vt);

    attn_kernel<<<dim3(64, 4, nsplit), 256, 0, stream>>>(
        qkT, Vt, xxb, Op, mp, lp, nsplit);

    if (nsplit > 1)
        combine_splits<<<dim3(4 * N_SP / 2), 256, 0, stream>>>(
            Op, mp, lp, xxb, nsplit);

    proj_out<<<dim3(4, 64, 4), 256, 0, stream>>>(xxb, wpf, shiftp, (float*)d_out);
}

// Round 6
// 164.552 us; speedup vs baseline: 1.4628x; 1.4628x over previous
//
#include <hip/hip_runtime.h>
#include <cstdint>
#include <cstddef>

// ---------------------------------------------------------------------------
// Attention_Param_sharing_Kv_sharing: B=4, C=256, H=W=64 (N=4096), KD=16,
// NH=8, DH=128.  qk projection shared between Q and K (Gram matrix), one KV
// head shared across 8 heads -> O = softmax(qk^T qk) @ V, V in R^{N x 128}.
//
// R4: 175 us, attn 137 us @ 11% occupancy (1 wave/SIMD, latency-bound).
// R5: global key-split x4 REGRESSED (211 us): 33 MB fp32 partial writes
//     flushed L2; per-tile latency inflated 3x.
// R6: in-block key-split x4 (4 waves x 1024 keys per 16 q-rows), partials
//     combined via LDS (24.6 KB) -- 4096 waves = 4/SIMD, zero extra global
//     traffic.  Plus deferred l-sum (per-lane partial, one reduction per
//     wave instead of 16 shfl per tile).  Inner S/V/PV code identical to
//     verified R4.
// ---------------------------------------------------------------------------

typedef __attribute__((ext_vector_type(4))) float f32x4;
typedef __attribute__((ext_vector_type(8))) _Float16 half8;
typedef __attribute__((ext_vector_type(8))) unsigned short ushort8;

#define N_SP 4096
#define CIN  256
#define KDIM 16
#define DHV  128

__device__ __forceinline__ unsigned short f2h(float f) {
    _Float16 h = (_Float16)f;             // RNE
    return __builtin_bit_cast(unsigned short, h);
}

__device__ __forceinline__ f32x4 mfma16(ushort8 a, ushort8 b, f32x4 c) {
    return __builtin_amdgcn_mfma_f32_16x16x32_f16(
        __builtin_bit_cast(half8, a), __builtin_bit_cast(half8, b), c, 0, 0, 0);
}

// ---------------------------------------------------------------------------
// Kernel 0: fold BN into weights (unchanged).
// ---------------------------------------------------------------------------
__global__ __launch_bounds__(256) void fold_weights(
    const float* __restrict__ w_qk, const float* __restrict__ g_qk,
    const float* __restrict__ b_qk, const float* __restrict__ m_qk,
    const float* __restrict__ v_qk,
    const float* __restrict__ w_v, const float* __restrict__ g_v,
    const float* __restrict__ b_v, const float* __restrict__ m_v,
    const float* __restrict__ v_v,
    const float* __restrict__ w_p, const float* __restrict__ g_p,
    const float* __restrict__ b_p, const float* __restrict__ m_p,
    const float* __restrict__ v_p,
    unsigned short* __restrict__ wf1, float* __restrict__ shift1,
    unsigned short* __restrict__ wpf, float* __restrict__ shiftp)
{
    int row = blockIdx.x;
    int t   = threadIdx.x;
    if (row < 144) {
        float s, sh; const float* src;
        if (row < KDIM) {
            s  = g_qk[row] * rsqrtf(v_qk[row] + 1e-5f);
            sh = b_qk[row] - m_qk[row] * s;
            src = w_qk + row * CIN;
        } else {
            int o = row - KDIM;
            s  = g_v[o] * rsqrtf(v_v[o] + 1e-5f);
            sh = b_v[o] - m_v[o] * s;
            src = w_v + o * CIN;
        }
        wf1[row * CIN + t] = f2h(src[t] * s);
        if (t == 0) shift1[row] = sh;
    } else {
        int o = row - 144;
        float s = g_p[o] * rsqrtf(v_p[o] + 1e-5f);
        if (t < DHV) wpf[o * DHV + t] = f2h(w_p[o * DHV + t] * s);
        if (t == 0) shiftp[o] = b_p[o] - m_p[o] * s;
    }
}

// ---------------------------------------------------------------------------
// Kernel 1: projection GEMM  [144 x 256] @ [256 x 4096] per batch.
// Grid (64, B): one block per 64-n tile; computes ALL 9 o-tiles so the
// x B-fragment is loaded once per ks and reused by 9 MFMAs (x read 1x).
// ---------------------------------------------------------------------------
__global__ __launch_bounds__(256) void proj_qkv(
    const float* __restrict__ x,
    const unsigned short* __restrict__ wf1, const float* __restrict__ shift1,
    unsigned short* __restrict__ qkT, unsigned short* __restrict__ Vt)
{
    const int b  = blockIdx.y;
    const int n0 = blockIdx.x * 64;
    const int tid  = threadIdx.x;
    const int w    = tid >> 6;
    const int lane = tid & 63;
    const int lg   = lane >> 4;
    const int lr   = lane & 15;
    const int n    = n0 + w * 16 + lr;

    const float* xb = x + (size_t)b * CIN * N_SP;
    f32x4 acc[9];
#pragma unroll
    for (int i = 0; i < 9; ++i) acc[i] = (f32x4){0.f, 0.f, 0.f, 0.f};

    for (int ks = 0; ks < 8; ++ks) {
        const int cbase = ks * 32 + lg * 8;
        ushort8 bx;
#pragma unroll
        for (int j = 0; j < 8; ++j) {
            float xv = xb[(size_t)(cbase + j) * N_SP + n];
            bx[j] = f2h(xv);
        }
#pragma unroll
        for (int ot = 0; ot < 9; ++ot) {
            ushort8 a = *(const ushort8*)(wf1 + (ot * 16 + lr) * CIN + cbase);
            acc[ot] = mfma16(a, bx, acc[ot]);
        }
    }

#pragma unroll
    for (int ot = 0; ot < 9; ++ot)
#pragma unroll
        for (int r = 0; r < 4; ++r) {
            int o = ot * 16 + lg * 4 + r;
            float val = acc[ot][r] + shift1[o];
            unsigned short hv = f2h(val);
            if (o < KDIM) qkT[((size_t)b * N_SP + n) * 32 + o] = hv;
            else          Vt[((size_t)b * DHV + (o - KDIM)) * N_SP + n] = hv;
        }

    // zero the K-padding columns 16..31 of qkT for this (b, n-tile)
    {
        int n_l  = tid >> 2;
        int part = tid & 3;
        unsigned long long* p = (unsigned long long*)
            (qkT + ((size_t)b * N_SP + n0 + n_l) * 32 + 16 + part * 4);
        *p = 0ULL;
    }
}

// ---------------------------------------------------------------------------
// Kernel 2: flash attention, in-block key-split.
// Grid (256, B), 256 thr = 4 waves.  Block owns 16 q-rows; wave w processes
// keys [w*1024, (w+1)*1024) (16 tiles of 64).  Per-wave partial (O~, m, l)
// in fp32; waves 1..3 publish via LDS; one __syncthreads; wave 0 merges
// (exp-weighted), normalizes, relu, stores xx.  l-sum is deferred: per-lane
// partial rescaled by sc each tile, one 4-shfl reduction per wave at end.
// ---------------------------------------------------------------------------
__global__ __launch_bounds__(256) void attn_kernel(
    const unsigned short* __restrict__ qkT,
    const unsigned short* __restrict__ Vt,
    unsigned short* __restrict__ xx)
{
    const int b  = blockIdx.y;
    const int q0 = blockIdx.x * 16;
    const int tid  = threadIdx.x;
    const int w    = tid >> 6;               // key-split index 0..3
    const int lane = tid & 63;
    const int lg   = lane >> 4;
    const int lr   = lane & 15;

    const unsigned short* qk_b = qkT + (size_t)b * N_SP * 32;
    const unsigned short* vt_b = Vt  + (size_t)b * DHV * N_SP;

    const int kbeg = w * (N_SP / 4);
    const int kend = kbeg + (N_SP / 4);

    const ushort8 aq = *(const ushort8*)(qk_b + (size_t)(q0 + lr) * 32 + lg * 8);

    f32x4 acc[8];
#pragma unroll
    for (int i = 0; i < 8; ++i) acc[i] = (f32x4){0.f, 0.f, 0.f, 0.f};
    float m_r[4] = {-__builtin_inff(), -__builtin_inff(),
                    -__builtin_inff(), -__builtin_inff()};
    float l_r[4] = {0.f, 0.f, 0.f, 0.f};     // per-lane partial sums

    __shared__ __align__(16) unsigned short p_lds[4][16][72];   // 9.2 KB
    __shared__ float part[3][16][DHV];                          // 24.6 KB
    __shared__ float pm[3][16], pl[3][16];                      // 384 B

    const f32x4 zero4 = {0.f, 0.f, 0.f, 0.f};

    for (int k0 = kbeg; k0 < kend; k0 += 64) {
        // ---- S = Q K^T for this wave's 16 queries x 64 keys -------------
        f32x4 s[4];
#pragma unroll
        for (int t = 0; t < 4; ++t) {
            ushort8 bk = *(const ushort8*)(qk_b + (size_t)(k0 + t * 16 + lr) * 32 + lg * 8);
            s[t] = mfma16(aq, bk, zero4);
        }

        // ---- hoist V-tile loads so L2 latency overlaps the softmax VALU --
        ushort8 vb[2][8];
#pragma unroll
        for (int ks = 0; ks < 2; ++ks)
#pragma unroll
            for (int nn = 0; nn < 8; ++nn)
                vb[ks][nn] = *(const ushort8*)
                    (vt_b + (size_t)(nn * 16 + lr) * N_SP + k0 + ks * 32 + lg * 8);

        // ---- online softmax (rows = lg*4+r, max-reduce over lane&15) -----
        float sc_r[4];
#pragma unroll
        for (int r = 0; r < 4; ++r) {
            float mx = fmaxf(fmaxf(s[0][r], s[1][r]), fmaxf(s[2][r], s[3][r]));
            mx = fmaxf(mx, __shfl_xor(mx, 1));
            mx = fmaxf(mx, __shfl_xor(mx, 2));
            mx = fmaxf(mx, __shfl_xor(mx, 4));
            mx = fmaxf(mx, __shfl_xor(mx, 8));
            float mnew = fmaxf(m_r[r], mx);
            float sc = __expf(m_r[r] - mnew);     // first iter: exp(-inf)=0
            float rs = 0.f;
#pragma unroll
            for (int t = 0; t < 4; ++t) {
                float p = __expf(s[t][r] - mnew);
                s[t][r] = p;
                rs += p;
            }
            l_r[r] = l_r[r] * sc + rs;            // deferred: per-lane partial
            m_r[r] = mnew;
            sc_r[r] = sc;
        }

        // ---- rescale accumulator ----------------------------------------
#pragma unroll
        for (int nn = 0; nn < 8; ++nn)
#pragma unroll
            for (int r = 0; r < 4; ++r) acc[nn][r] *= sc_r[r];

        // ---- P -> LDS transpose (per-wave region, no barrier needed) -----
#pragma unroll
        for (int t = 0; t < 4; ++t)
#pragma unroll
            for (int r = 0; r < 4; ++r)
                p_lds[w][lg * 4 + r][t * 16 + lr] = f2h(s[t][r]);

        // ---- O += P @ V --------------------------------------------------
#pragma unroll
        for (int ks = 0; ks < 2; ++ks) {
            ushort8 pa = *(const ushort8*)(&p_lds[w][lr][ks * 32 + lg * 8]);
#pragma unroll
            for (int nn = 0; nn < 8; ++nn)
                acc[nn] = mfma16(pa, vb[ks][nn], acc[nn]);
        }
    }

    // ---- finish deferred l: reduce across lane&15 ------------------------
#pragma unroll
    for (int r = 0; r < 4; ++r) {
        float rs = l_r[r];
        rs += __shfl_xor(rs, 1);
        rs += __shfl_xor(rs, 2);
        rs += __shfl_xor(rs, 4);
        rs += __shfl_xor(rs, 8);
        l_r[r] = rs;
    }

    // ---- publish partials (waves 1..3) -----------------------------------
    if (w > 0) {
#pragma unroll
        for (int r = 0; r < 4; ++r) {
            int row = lg * 4 + r;
#pragma unroll
            for (int nn = 0; nn < 8; ++nn)
                part[w - 1][row][nn * 16 + lr] = acc[nn][r];
            if (lr == 0) { pm[w - 1][row] = m_r[r]; pl[w - 1][row] = l_r[r]; }
        }
    }
    __syncthreads();

    // ---- wave 0: exp-weighted merge, normalize, relu, store --------------
    if (w == 0) {
        const size_t xoff = (size_t)b * N_SP * DHV;
#pragma unroll
        for (int r = 0; r < 4; ++r) {
            int row = lg * 4 + r;
            float M = m_r[r];
            M = fmaxf(M, pm[0][row]);
            M = fmaxf(M, pm[1][row]);
            M = fmaxf(M, pm[2][row]);
            float w0  = __expf(m_r[r]    - M);
            float ws0 = __expf(pm[0][row] - M);
            float ws1 = __expf(pm[1][row] - M);
            float ws2 = __expf(pm[2][row] - M);
            float L = l_r[r] * w0 + pl[0][row] * ws0
                    + pl[1][row] * ws1 + pl[2][row] * ws2;
            float inv = 1.0f / L;
            int q = q0 + row;
#pragma unroll
            for (int nn = 0; nn < 8; ++nn) {
                int d = nn * 16 + lr;
                float o = acc[nn][r] * w0
                        + part[0][row][d] * ws0
                        + part[1][row][d] * ws1
                        + part[2][row][d] * ws2;
                xx[xoff + (size_t)q * DHV + d] = f2h(fmaxf(o * inv, 0.f));
            }
        }
    }
}

// ---------------------------------------------------------------------------
// Kernel 3: output projection (unchanged).
// ---------------------------------------------------------------------------
__global__ __launch_bounds__(256) void proj_out(
    const unsigned short* __restrict__ xx,
    const unsigned short* __restrict__ wpf, const float* __restrict__ shiftp,
    float* __restrict__ out)
{
    const int b  = blockIdx.z;
    const int n0 = blockIdx.y * 64;
    const int o0 = blockIdx.x * 64 + (threadIdx.x >> 6) * 16;
    const int lane = threadIdx.x & 63;
    const int lg   = lane >> 4;
    const int lr   = lane & 15;

    f32x4 acc[4];
#pragma unroll
    for (int i = 0; i < 4; ++i) acc[i] = (f32x4){0.f, 0.f, 0.f, 0.f};

    const unsigned short* xb = xx + (size_t)b * N_SP * DHV;

    for (int ks = 0; ks < 4; ++ks) {
        ushort8 a = *(const ushort8*)(wpf + (size_t)(o0 + lr) * DHV + ks * 32 + lg * 8);
#pragma unroll
        for (int nt = 0; nt < 4; ++nt) {
            ushort8 bfr = *(const ushort8*)
                (xb + (size_t)(n0 + nt * 16 + lr) * DHV + ks * 32 + lg * 8);
            acc[nt] = mfma16(a, bfr, acc[nt]);
        }
    }

#pragma unroll
    for (int nt = 0; nt < 4; ++nt)
#pragma unroll
        for (int r = 0; r < 4; ++r) {
            int o = o0 + lg * 4 + r;
            out[((size_t)b * CIN + o) * N_SP + n0 + nt * 16 + lr]
                = acc[nt][r] + shiftp[o];
        }
}

// ---------------------------------------------------------------------------
extern "C" void kernel_launch(void* const* d_in, const int* in_sizes, int n_in,
                              void* d_out, int out_size, void* d_ws, size_t ws_size,
                              hipStream_t stream)
{
    const float* x    = (const float*)d_in[0];
    const float* w_qk = (const float*)d_in[2];
    const float* g_qk = (const float*)d_in[3];
    const float* b_qk = (const float*)d_in[4];
    const float* m_qk = (const float*)d_in[5];
    const float* v_qk = (const float*)d_in[6];
    const float* w_v  = (const float*)d_in[7];
    const float* g_v  = (const float*)d_in[8];
    const float* b_v  = (const float*)d_in[9];
    const float* m_v  = (const float*)d_in[10];
    const float* v_v  = (const float*)d_in[11];
    const float* w_p  = (const float*)d_in[12];
    const float* g_p  = (const float*)d_in[13];
    const float* b_p  = (const float*)d_in[14];
    const float* m_p  = (const float*)d_in[15];
    const float* v_p  = (const float*)d_in[16];

    char* ws = (char*)d_ws;
    unsigned short* qkT = (unsigned short*)(ws);                    // 1 MB
    unsigned short* Vt  = (unsigned short*)(ws + (1u << 20));       // 4 MB
    unsigned short* xxb = (unsigned short*)(ws + (5u << 20));       // 4 MB
    unsigned short* wf1 = (unsigned short*)(ws + (9u << 20));       // 72 KB
    float* shift1       = (float*)(ws + (9u << 20) + 80 * 1024);    // 576 B
    unsigned short* wpf = (unsigned short*)(ws + (9u << 20) + 84 * 1024); // 64 KB
    float* shiftp       = (float*)(ws + (9u << 20) + 148 * 1024);   // 1 KB

    fold_weights<<<400, 256, 0, stream>>>(
        w_qk, g_qk, b_qk, m_qk, v_qk,
        w_v, g_v, b_v, m_v, v_v,
        w_p, g_p, b_p, m_p, v_p,
        wf1, shift1, wpf, shiftp);

    proj_qkv<<<dim3(64, 4), 256, 0, stream>>>(x, wf1, shift1, qkT, Vt);

    attn_kernel<<<dim3(256, 4), 256, 0, stream>>>(qkT, Vt, xxb);

    proj_out<<<dim3(4, 64, 4), 256, 0, stream>>>(xxb, wpf, shiftp, (float*)d_out);
}